// Round 5
// baseline (233.314 us; speedup 1.0000x reference)
//
#include <hip/hip_runtime.h>
#include <math.h>

#define VOCAB 32000
#define D 768
#define S 512
#define W 300
#define B 64
#define LMAX 4
#define GW 4                 // words per group = waves per block
#define GPB 75               // groups per batch = W/GW
#define NGRP (B * GPB)       // 4800
#define MAXROWS 12           // GW * max span (3)
#define ROWB 3072            // bytes per 768-float row
#define BUFB (MAXROWS * ROWB)// 36864 per buffer
#define NBLK 512             // persistent-ish grid: 2 blocks/CU

typedef float f32x4 __attribute__((ext_vector_type(4)));

// ---------------------------------------------------------------------------
// Kernel 1: per-batch "first break" scan.
// ---------------------------------------------------------------------------
__global__ __launch_bounds__(64) void find_first_kernel(
    const int* __restrict__ word_index,  // (B, W, 3)
    int* __restrict__ first_out,         // (B)
    int* __restrict__ fill_id_out)       // (B)
{
    const int b = blockIdx.x;
    const int lane = threadIdx.x;  // 0..63
    int my_first = W;
    for (int w = lane; w < W; w += 64) {
        const int base = (b * W + w) * 3;
        const int st = word_index[base + 1];
        const int en = word_index[base + 2];
        if (en < S && (en - st) <= 0) my_first = min(my_first, w);
    }
    #pragma unroll
    for (int off = 32; off > 0; off >>= 1)
        my_first = min(my_first, __shfl_xor(my_first, off));
    if (lane == 0) {
        first_out[b] = my_first;
        const int fw = min(my_first, W - 1);
        fill_id_out[b] = word_index[(b * W + fw) * 3 + 0];
    }
}

__device__ __forceinline__ float wave_bcast_sum(float p) {
    #pragma unroll
    for (int off = 32; off > 0; off >>= 1) p += __shfl_xor(p, off);
    return p;
}

// async global->LDS, 16B per lane; LDS dst = wave-uniform base + lane*16.
__device__ __forceinline__ void async_copy16(const void* g, void* l) {
    __builtin_amdgcn_global_load_lds(
        (const __attribute__((address_space(1))) void*)g,
        (__attribute__((address_space(3))) void*)l,
        16, 0, 0);
}

// ---------------------------------------------------------------------------
// Kernel 2: persistent double-buffered variant.
// Each block owns groups {blockIdx, blockIdx+NBLK, ...}; per group (4 words,
// one wave each) the contiguous ernie row range [st0, min(en3,S)) (<=12 rows)
// is async-staged into the inactive LDS buffer WHILE the active buffer's
// group is being computed; the barrier-drain thus lands after a full compute
// phase of overlap (unlike R4's issue->drain->compute).
// ---------------------------------------------------------------------------

__device__ __forceinline__ int stage_group(
    const float* __restrict__ ernie, const int* __restrict__ word_index,
    int g, char* __restrict__ buf, int waveid, int lane)
{
    const int b  = g / GPB;
    const int w0 = (g - b * GPB) * GW;
    const int st0 = word_index[(b * W + w0) * 3 + 1];
    const int en3 = word_index[(b * W + w0 + GW - 1) * 3 + 2];
    const int row_lo = max(min(st0, S), 0);
    const int row_hi = min(en3, S);
    const int nrows  = min(max(row_hi - row_lo, 0), MAXROWS);
    const char* gbase = (const char*)(ernie + ((size_t)b * S + row_lo) * D);
    const int nchunk = nrows * 3;   // 1 KB chunks
    for (int c = waveid; c < nchunk; c += GW)
        async_copy16(gbase + c * 1024 + lane * 16, buf + c * 1024);
    return row_lo;
}

__device__ __forceinline__ void load_we(
    int g, int waveid, int lane, const int* __restrict__ word_index,
    const int* __restrict__ first_arr, const int* __restrict__ fill_arr,
    const float* __restrict__ emb, f32x4& we0, f32x4& we1, f32x4& we2)
{
    const int b = g / GPB;
    const int w = (g - b * GPB) * GW + waveid;
    const int gword = b * W + w;
    const int wid = word_index[gword * 3 + 0];
    const int rowid = (w >= first_arr[b]) ? fill_arr[b] : wid;
    const f32x4* wep = (const f32x4*)(emb + (size_t)rowid * D);
    we0 = wep[lane]; we1 = wep[lane + 64]; we2 = wep[lane + 128];
}

__device__ __forceinline__ void compute_word(
    int g, int waveid, int lane, const char* __restrict__ buf, int row_lo,
    f32x4 we0, f32x4 we1, f32x4 we2,
    const int* __restrict__ word_index, const int* __restrict__ first_arr,
    float* __restrict__ out)
{
    const int b = g / GPB;
    const int w = (g - b * GPB) * GW + waveid;
    const int gword = b * W + w;
    const int st = word_index[gword * 3 + 1];
    const int en = word_index[gword * 3 + 2];
    f32x4* __restrict__ outp = (f32x4*)(out + (size_t)gword * D);

    // fill path (we regs already hold emb[fill_id]) or out-of-range copy
    if (w >= first_arr[b] || en >= S) {
        __builtin_nontemporal_store(we0, &outp[lane]);
        __builtin_nontemporal_store(we1, &outp[lane + 64]);
        __builtin_nontemporal_store(we2, &outp[lane + 128]);
        return;
    }

    const int span_eff = min(max(en - st, 1), LMAX);
    const char* lbase = buf + (size_t)(st - row_lo) * ROWB;

    float m = -INFINITY, denom = 0.f;
    f32x4 acc0 = 0.f, acc1 = 0.f, acc2 = 0.f;

    #pragma unroll
    for (int l = 0; l < LMAX; ++l) {
        if (l >= span_eff) break;   // scalar branch
        const f32x4* cp = (const f32x4*)(lbase + l * ROWB);
        f32x4 c0 = cp[lane];
        f32x4 c1 = cp[lane + 64];
        f32x4 c2 = cp[lane + 128];
        f32x4 pv = c0 * we0 + c1 * we1 + c2 * we2;
        float p = pv.x + pv.y + pv.z + pv.w;
        p = wave_bcast_sum(p);
        float mn = fmaxf(m, p);
        float scale = expf(m - mn);     // 1st iter: expf(-inf)=0
        float e = expf(p - mn);
        denom = denom * scale + e;
        acc0 = acc0 * scale + e * c0;
        acc1 = acc1 * scale + e * c1;
        acc2 = acc2 * scale + e * c2;
        m = mn;
    }

    const float inv = 1.f / denom;
    __builtin_nontemporal_store(acc0 * inv, &outp[lane]);
    __builtin_nontemporal_store(acc1 * inv, &outp[lane + 64]);
    __builtin_nontemporal_store(acc2 * inv, &outp[lane + 128]);
}

__global__ __launch_bounds__(256) void pool_kernel(
    const float* __restrict__ ernie,      // (B, S, D)
    const float* __restrict__ emb,        // (VOCAB, D)
    const int*   __restrict__ word_index, // (B, W, 3)
    const int*   __restrict__ first_arr,  // (B)
    const int*   __restrict__ fill_arr,   // (B)
    float* __restrict__ out)              // (B, W, D)
{
    __shared__ __align__(16) char smem[2][BUFB];

    const int lane   = threadIdx.x & 63;
    const int waveid = __builtin_amdgcn_readfirstlane(threadIdx.x >> 6);

    int g = blockIdx.x;
    // prologue: fill slot A
    int rowA = stage_group(ernie, word_index, g, smem[0], waveid, lane);
    f32x4 aw0, aw1, aw2;
    load_we(g, waveid, lane, word_index, first_arr, fill_arr, emb, aw0, aw1, aw2);
    int rowB = 0;
    f32x4 bw0, bw1, bw2;

    for (;;) {
        // ---- compute slot A; prefetch into slot B ----
        int gn = g + NBLK;
        __syncthreads();                       // smem[0] + we(g) ready
        const bool hasN1 = (gn < NGRP);        // block-uniform
        if (hasN1) {
            rowB = stage_group(ernie, word_index, gn, smem[1], waveid, lane);
            load_we(gn, waveid, lane, word_index, first_arr, fill_arr, emb,
                    bw0, bw1, bw2);
        }
        compute_word(g, waveid, lane, smem[0], rowA, aw0, aw1, aw2,
                     word_index, first_arr, out);
        if (!hasN1) return;
        g = gn;

        // ---- compute slot B; prefetch into slot A ----
        gn = g + NBLK;
        __syncthreads();                       // smem[1] + we(g) ready
        const bool hasN2 = (gn < NGRP);
        if (hasN2) {
            rowA = stage_group(ernie, word_index, gn, smem[0], waveid, lane);
            load_we(gn, waveid, lane, word_index, first_arr, fill_arr, emb,
                    aw0, aw1, aw2);
        }
        compute_word(g, waveid, lane, smem[1], rowB, bw0, bw1, bw2,
                     word_index, first_arr, out);
        if (!hasN2) return;
        g = gn;
    }
}

extern "C" void kernel_launch(void* const* d_in, const int* in_sizes, int n_in,
                              void* d_out, int out_size, void* d_ws, size_t ws_size,
                              hipStream_t stream) {
    const float* ernie      = (const float*)d_in[0];  // (B, S, D) fp32
    const float* emb        = (const float*)d_in[1];  // (VOCAB, D) fp32
    const int*   word_index = (const int*)d_in[2];    // (B, W, 3) int32
    float* out = (float*)d_out;                       // (B, W, D) fp32

    int* first_arr = (int*)d_ws;        // B ints
    int* fill_arr  = first_arr + B;     // B ints

    find_first_kernel<<<B, 64, 0, stream>>>(word_index, first_arr, fill_arr);

    pool_kernel<<<NBLK, 256, 0, stream>>>(ernie, emb, word_index,
                                          first_arr, fill_arr, out);
}